// Round 1
// baseline (285.861 us; speedup 1.0000x reference)
//
#include <hip/hip_runtime.h>

typedef unsigned short u16;
typedef __bf16 bf8 __attribute__((ext_vector_type(8)));
typedef float f4 __attribute__((ext_vector_type(4)));

typedef __attribute__((address_space(1))) const unsigned int gas_u32;
typedef __attribute__((address_space(3))) unsigned int las_u32;
#define ASYNC16(g, l) __builtin_amdgcn_global_load_lds((gas_u32*)(g), (las_u32*)(l), 16, 0, 0)

__device__ __forceinline__ u16 f2bf(float f) {
    union { float f; unsigned int u; } v; v.f = f;
    return (u16)((v.u + 0x7fffu + ((v.u >> 16) & 1u)) >> 16);
}

// ---------------- fp32 -> bf16 conversion of inputs + weights ----------------
// ws regions (elements): xk@0, xq@4194304, xv@8388608, Wq@12582912, Wk@13631488,
// Wv@14680064, Wo@15728640  (region order matches concatenated source order)
__global__ __launch_bounds__(256) void cvt_all(
    const float* __restrict__ k_, const float* __restrict__ q_, const float* __restrict__ v_,
    const float* __restrict__ wq, const float* __restrict__ wk, const float* __restrict__ wv,
    const float* __restrict__ wo, u16* __restrict__ ws) {
  size_t e = ((size_t)blockIdx.x * 256 + threadIdx.x) * 8;
  const float* src;
  if      (e <  4194304) src = k_ + e;
  else if (e <  8388608) src = q_ + (e - 4194304);
  else if (e < 12582912) src = v_ + (e - 8388608);
  else if (e < 13631488) src = wq + (e - 12582912);
  else if (e < 14680064) src = wk + (e - 13631488);
  else if (e < 15728640) src = wv + (e - 14680064);
  else                   src = wo + (e - 15728640);
  float4 f0 = ((const float4*)src)[0];
  float4 f1 = ((const float4*)src)[1];
  uint4 o;
  o.x = (unsigned)f2bf(f0.x) | ((unsigned)f2bf(f0.y) << 16);
  o.y = (unsigned)f2bf(f0.z) | ((unsigned)f2bf(f0.w) << 16);
  o.z = (unsigned)f2bf(f1.x) | ((unsigned)f2bf(f1.y) << 16);
  o.w = (unsigned)f2bf(f1.z) | ((unsigned)f2bf(f1.w) << 16);
  *(uint4*)(ws + e) = o;
}

// ---------------- m97-style 128x128 GEMM, C = A[M,K] @ B[N,K]^T ----------------
// M=4096, N=1024, K=1024. 256 threads = 2x2 waves of 64x64. BK=32.
template<bool FINAL>
__device__ __forceinline__ void gemm128(const u16* __restrict__ A, const u16* __restrict__ Bm,
                                        u16* __restrict__ Cb, float* __restrict__ Cf,
                                        const float* __restrict__ bias) {
  __shared__ u16 As[128*32];
  __shared__ u16 Bs[128*32];
  const int tid = threadIdx.x;
  const int wave = tid >> 6, lane = tid & 63;
  const int wm = wave >> 1, wn = wave & 1;
  const int quad = lane >> 4, l16 = lane & 15;
  const int bm = blockIdx.y, bn = blockIdx.x;

  f4 acc[4][4];
  const f4 zz = {0.f, 0.f, 0.f, 0.f};
  #pragma unroll
  for (int i = 0; i < 4; i++)
    #pragma unroll
    for (int j = 0; j < 4; j++) acc[i][j] = zz;

  const u16* ga = A  + (size_t)(bm*128 + wave*16 + (lane>>2)) * 1024 + (lane&3)*8;
  const u16* gb = Bm + (size_t)(bn*128 + wave*16 + (lane>>2)) * 1024 + (lane&3)*8;
  u16* la = As + wave*512 + lane*8;   // == row-major [row][32] dest, wave-uniform base + lane*16B
  u16* lb = Bs + wave*512 + lane*8;

  for (int kt = 0; kt < 1024; kt += 32) {
    ASYNC16(ga,           la);
    ASYNC16(ga + 64*1024, la + 2048);
    ASYNC16(gb,           lb);
    ASYNC16(gb + 64*1024, lb + 2048);
    ga += 32; gb += 32;
    __syncthreads();
    bf8 af[4];
    #pragma unroll
    for (int mi = 0; mi < 4; mi++)
      af[mi] = *(const bf8*)(As + (wm*64 + mi*16 + l16)*32 + quad*8);
    #pragma unroll
    for (int ni = 0; ni < 4; ni++) {
      bf8 bfr = *(const bf8*)(Bs + (wn*64 + ni*16 + l16)*32 + quad*8);
      #pragma unroll
      for (int mi = 0; mi < 4; mi++)
        acc[mi][ni] = __builtin_amdgcn_mfma_f32_16x16x32_bf16(af[mi], bfr, acc[mi][ni], 0, 0, 0);
    }
    __syncthreads();
  }

  #pragma unroll
  for (int mi = 0; mi < 4; mi++)
    #pragma unroll
    for (int ni = 0; ni < 4; ni++) {
      const int col = bn*128 + wn*64 + ni*16 + l16;
      #pragma unroll
      for (int r = 0; r < 4; r++) {
        const int row = bm*128 + wm*64 + mi*16 + quad*4 + r;
        if (FINAL) Cf[(size_t)row*1024 + col] = acc[mi][ni][r] + bias[col];
        else       Cb[(size_t)row*1024 + col] = f2bf(acc[mi][ni][r]);
      }
    }
}

__global__ __launch_bounds__(256, 2) void gemm_qkv(
    const u16* __restrict__ xq, const u16* __restrict__ xk, const u16* __restrict__ xv,
    const u16* __restrict__ wq, const u16* __restrict__ wk, const u16* __restrict__ wv,
    u16* __restrict__ Qo, u16* __restrict__ Ko, u16* __restrict__ Vo) {
  const u16 *A, *Bw; u16 *C;
  if (blockIdx.z == 0)      { A = xq; Bw = wq; C = Qo; }
  else if (blockIdx.z == 1) { A = xk; Bw = wk; C = Ko; }
  else                      { A = xv; Bw = wv; C = Vo; }
  gemm128<false>(A, Bw, C, nullptr, nullptr);
}

__global__ __launch_bounds__(256, 2) void gemm_out(
    const u16* __restrict__ ctx, const u16* __restrict__ wo,
    const float* __restrict__ bias, float* __restrict__ out) {
  gemm128<true>(ctx, wo, nullptr, out, bias);
}

// ---------------- flash attention: 128 Q-rows per block, per (qtile, head, batch) ----------------
// Q,K,V,ctx are bf16 [B*S, 1024] with head h at columns h*64..h*64+63.
// LDS strides padded (72/136 halves) so all ds_read_b128 patterns are <=2-way (free, m136).
__global__ __launch_bounds__(256, 2) void flash_attn(
    const u16* __restrict__ Qg, const u16* __restrict__ Kg,
    const u16* __restrict__ Vg, u16* __restrict__ ctx) {
  __shared__ u16 Ks[128*72];     // [key][dim], stride 72
  __shared__ u16 Vt[64*136];     // [dim][key], stride 136 (transposed V)
  __shared__ u16 Pl[4*32*72];    // per-wave P half-tile [32 rows][64 keys], stride 72
  const int tid = threadIdx.x;
  const int wave = tid >> 6, lane = tid & 63;
  const int quad = lane >> 4, l16 = lane & 15;
  const int qt = blockIdx.x, h = blockIdx.y, b = blockIdx.z;
  u16* Pw = Pl + wave*(32*72);

  // Q fragments (A-layout: A[m=l16][k=quad*8+j]), rows wave*32 + mi*16 + l16, direct from global
  bf8 aq[2][2];
  {
    const u16* qp = Qg + (size_t)(b*2048 + qt*128 + wave*32) * 1024 + h*64;
    #pragma unroll
    for (int mi = 0; mi < 2; mi++)
      #pragma unroll
      for (int kc = 0; kc < 2; kc++)
        aq[mi][kc] = *(const bf8*)(qp + (size_t)(mi*16 + l16)*1024 + kc*32 + quad*8);
  }

  const f4 zz = {0.f, 0.f, 0.f, 0.f};
  f4 acc_o[2][4];
  float mrow[2][4], lrow[2][4];
  #pragma unroll
  for (int mi = 0; mi < 2; mi++) {
    #pragma unroll
    for (int nd = 0; nd < 4; nd++) acc_o[mi][nd] = zz;
    #pragma unroll
    for (int r = 0; r < 4; r++) { mrow[mi][r] = -1e30f; lrow[mi][r] = 0.f; }
  }

  // staging maps
  const int kkey = tid >> 3, kchunk = tid & 7;                 // K: coalesced 128B/key
  const u16* gK = Kg + (size_t)(b*2048 + kkey)*1024 + h*64 + kchunk*8;
  u16* lK = Ks + kkey*72 + kchunk*8;
  const int vkey = tid & 127, vdb = (tid >> 7)*8;              // V: lane<->key so LDS writes are 2-way
  const u16* gV = Vg + (size_t)(b*2048 + vkey)*1024 + h*64 + vdb;

  for (int kv0 = 0; kv0 < 2048; kv0 += 128) {
    __syncthreads();   // protect Ks/Vt from overwrite while prior iter still reading
    #pragma unroll
    for (int p = 0; p < 4; p++) {
      uint4 t4 = *(const uint4*)(gK + (size_t)(kv0 + p*32)*1024);
      *(uint4*)(lK + (p*32)*72) = t4;
    }
    #pragma unroll
    for (int p = 0; p < 4; p++) {
      uint4 t4 = *(const uint4*)(gV + (size_t)kv0*1024 + p*16);
      const u16* s = (const u16*)&t4;
      #pragma unroll
      for (int j = 0; j < 8; j++)
        Vt[(vdb + p*16 + j)*136 + vkey] = s[j];
    }
    __syncthreads();

    // S = Q @ K^T  (32 q-rows x 128 keys per wave)
    f4 sa[2][8];
    #pragma unroll
    for (int mi = 0; mi < 2; mi++)
      #pragma unroll
      for (int ni = 0; ni < 8; ni++) sa[mi][ni] = zz;
    #pragma unroll
    for (int ni = 0; ni < 8; ni++) {
      bf8 bk0 = *(const bf8*)(Ks + (ni*16 + l16)*72 + quad*8);
      bf8 bk1 = *(const bf8*)(Ks + (ni*16 + l16)*72 + 32 + quad*8);
      #pragma unroll
      for (int mi = 0; mi < 2; mi++) {
        sa[mi][ni] = __builtin_amdgcn_mfma_f32_16x16x32_bf16(aq[mi][0], bk0, sa[mi][ni], 0, 0, 0);
        sa[mi][ni] = __builtin_amdgcn_mfma_f32_16x16x32_bf16(aq[mi][1], bk1, sa[mi][ni], 0, 0, 0);
      }
    }

    // online softmax (rows live in C/D layout: row = mi*16 + quad*4 + r, col = ni*16 + l16)
    #pragma unroll
    for (int mi = 0; mi < 2; mi++)
      #pragma unroll
      for (int r = 0; r < 4; r++) {
        float mx = sa[mi][0][r];
        #pragma unroll
        for (int ni = 1; ni < 8; ni++) mx = fmaxf(mx, sa[mi][ni][r]);
        mx = fmaxf(mx, __shfl_xor(mx, 1));
        mx = fmaxf(mx, __shfl_xor(mx, 2));
        mx = fmaxf(mx, __shfl_xor(mx, 4));
        mx = fmaxf(mx, __shfl_xor(mx, 8));
        mx *= 0.125f;                      // 1/sqrt(64)
        float mn = fmaxf(mrow[mi][r], mx);
        float a  = __expf(mrow[mi][r] - mn);
        mrow[mi][r] = mn;
        float rs = 0.f;
        #pragma unroll
        for (int ni = 0; ni < 8; ni++) {
          float pv = __expf(sa[mi][ni][r] * 0.125f - mn);
          sa[mi][ni][r] = pv;
          rs += pv;
        }
        rs += __shfl_xor(rs, 1);
        rs += __shfl_xor(rs, 2);
        rs += __shfl_xor(rs, 4);
        rs += __shfl_xor(rs, 8);
        lrow[mi][r] = lrow[mi][r]*a + rs;
        #pragma unroll
        for (int nd = 0; nd < 4; nd++)
          acc_o[mi][nd][r] *= a;
      }

    // P (C-layout) -> LDS -> A-layout, then O += P @ V. Two 64-key halves reuse the P buffer.
    #pragma unroll
    for (int half = 0; half < 2; half++) {
      #pragma unroll
      for (int mi = 0; mi < 2; mi++)
        #pragma unroll
        for (int ni = 0; ni < 4; ni++)
          #pragma unroll
          for (int r = 0; r < 4; r++)
            Pw[(mi*16 + quad*4 + r)*72 + ni*16 + l16] = f2bf(sa[mi][half*4 + ni][r]);
      #pragma unroll
      for (int kc = 0; kc < 2; kc++) {
        bf8 ap0 = *(const bf8*)(Pw + (l16)*72      + kc*32 + quad*8);
        bf8 ap1 = *(const bf8*)(Pw + (16 + l16)*72 + kc*32 + quad*8);
        #pragma unroll
        for (int nd = 0; nd < 4; nd++) {
          bf8 bv = *(const bf8*)(Vt + (nd*16 + l16)*136 + half*64 + kc*32 + quad*8);
          acc_o[0][nd] = __builtin_amdgcn_mfma_f32_16x16x32_bf16(ap0, bv, acc_o[0][nd], 0, 0, 0);
          acc_o[1][nd] = __builtin_amdgcn_mfma_f32_16x16x32_bf16(ap1, bv, acc_o[1][nd], 0, 0, 0);
        }
      }
    }
  }

  // normalize and store ctx (bf16, [B*S, 1024], head h at cols h*64..)
  const size_t ob = (size_t)(b*2048 + qt*128 + wave*32) * 1024 + h*64;
  #pragma unroll
  for (int mi = 0; mi < 2; mi++)
    #pragma unroll
    for (int r = 0; r < 4; r++) {
      float inv = 1.f / lrow[mi][r];
      #pragma unroll
      for (int nd = 0; nd < 4; nd++)
        ctx[ob + (size_t)(mi*16 + quad*4 + r)*1024 + nd*16 + l16] = f2bf(acc_o[mi][nd][r] * inv);
    }
}

extern "C" void kernel_launch(void* const* d_in, const int* in_sizes, int n_in,
                              void* d_out, int out_size, void* d_ws, size_t ws_size,
                              hipStream_t stream) {
  const float* key_  = (const float*)d_in[0];
  const float* query = (const float*)d_in[1];
  const float* value = (const float*)d_in[2];
  const float* Wq = (const float*)d_in[3];
  const float* Wk = (const float*)d_in[4];
  const float* Wv = (const float*)d_in[5];
  const float* Wo = (const float*)d_in[6];
  const float* bo = (const float*)d_in[7];
  float* out = (float*)d_out;

  u16* ws  = (u16*)d_ws;                 // needs 67.1 MB of workspace
  u16* xkb = ws;                         // bf16(key)
  u16* xqb = ws + 4194304;               // bf16(query)
  u16* xvb = ws + 8388608;               // bf16(value)
  u16* Wqb = ws + 12582912;
  u16* Wkb = ws + 13631488;
  u16* Wvb = ws + 14680064;
  u16* Wob = ws + 15728640;
  u16* Qb  = ws + 16777216;              // Q = query @ Wq^T   [4096,1024] bf16
  u16* Kb  = ws + 20971520;
  u16* Vb  = ws + 25165824;
  u16* Cb  = ws + 29360128;              // attention context  [4096,1024] bf16

  cvt_all<<<8192, 256, 0, stream>>>(key_, query, value, Wq, Wk, Wv, Wo, ws);
  gemm_qkv<<<dim3(8, 32, 3), 256, 0, stream>>>(xqb, xkb, xvb, Wqb, Wkb, Wvb, Qb, Kb, Vb);
  flash_attn<<<dim3(16, 16, 2), 256, 0, stream>>>(Qb, Kb, Vb, Cb);
  gemm_out<<<dim3(8, 32, 1), 256, 0, stream>>>(Cb, Wob, bo, out);
}